// Round 4
// baseline (252.952 us; speedup 1.0000x reference)
//
#include <hip/hip_runtime.h>
#include <math.h>

#define L_SEQ 32768
#define H_DIM 512
#define P_DIM 256
#define K_DIM 512
#define CHUNK 32
#define NCHUNK (L_SEQ / CHUNK)   // 1024

typedef __bf16 bf16x8 __attribute__((ext_vector_type(8)));
typedef float floatx4 __attribute__((ext_vector_type(4)));

__device__ __forceinline__ void gll16(const void* g, void* l) {
    __builtin_amdgcn_global_load_lds(
        (__attribute__((address_space(1))) void*)(g),
        (__attribute__((address_space(3))) void*)(l), 16, 0, 0);
}

// B2[2p, h] = Bre[p,h]; B2[2p+1, h] = Bim[p,h]   (512 x 512 bf16)
__global__ __launch_bounds__(512) void build_b2_kernel(
    const float* __restrict__ Bre, const float* __restrict__ Bim,
    __bf16* __restrict__ B2)
{
    const int p = blockIdx.x;     // 0..255
    const int h = threadIdx.x;    // 0..511
    B2[(2 * p) * 512 + h]     = (__bf16)Bre[p * H_DIM + h];
    B2[(2 * p + 1) * 512 + h] = (__bf16)Bim[p * H_DIM + h];
}

// C2[h, 2p] = Cre[h,p]; C2[h, 2p+1] = -Cim[h,p]   (512 x 512 bf16)
__global__ __launch_bounds__(256) void build_c2_kernel(
    const float* __restrict__ Cre, const float* __restrict__ Cim,
    __bf16* __restrict__ C2)
{
    const int h = blockIdx.x;     // 0..511
    const int p = threadIdx.x;    // 0..255
    C2[h * 512 + 2 * p]     = (__bf16)Cre[h * P_DIM + p];
    C2[h * 512 + 2 * p + 1] = (__bf16)(-Cim[h * P_DIM + p]);
}

// ---------------------------------------------------------------------------
// GEMM1: G2[l,j] = sum_h U[l,h]*B2[j,h].
// Double-buffered single-barrier-per-phase pipeline: loads for tile t+1
// (A fp32->regs, B global_load_lds into alternate buffer) are issued BEFORE
// compute(t); the bf16 cvt + ds_write of A lands after compute(t); one
// __syncthreads per phase drains vmcnt+lgkmcnt.  Prefetch depth 1.
// ---------------------------------------------------------------------------
__global__ __launch_bounds__(256) void gemm1_kernel(
    const float* __restrict__ A,     // L x 512 fp32 (U)
    const __bf16* __restrict__ Bm,   // 512 x 512 bf16 (B2)
    __bf16* __restrict__ Out)        // L x 512 bf16 (G2)
{
    __shared__ __bf16 As[2][128 * 32];   // 8 KB each
    __shared__ __bf16 Bs[2][128 * 32];   // 8 KB each

    const int tid = threadIdx.x;
    const int w  = tid >> 6;
    const int ln = tid & 63;
    const int bm = blockIdx.x;
    const int bn = blockIdx.y;

    floatx4 acc[4][4];
    #pragma unroll
    for (int i = 0; i < 4; ++i)
        #pragma unroll
        for (int j = 0; j < 4; ++j)
            acc[i][j] = (floatx4){0.f, 0.f, 0.f, 0.f};

    // A reg-staging: thread -> row ar = tid>>1 (2 threads/row), 16 floats each
    const int ar = tid >> 1;
    const int ac = (tid & 1) << 4;
    const float* Ag = A + (size_t)(bm * 128 + ar) * K_DIM + ac;
    __bf16* const aw0 = &As[0][ar * 32 + ac];
    __bf16* const aw1 = &As[1][ar * 32 + ac];

    // B staging via gll16: wave w stages rows w*16..+15 and +64
    const size_t brow = (size_t)(bn * 128 + w * 16 + (ln >> 2)) * K_DIM
                      + ((ln & 3) << 3);
    __bf16* const bw0_0 = &Bs[0][w * 512];
    __bf16* const bw0_1 = &Bs[0][2048 + w * 512];
    __bf16* const bw1_0 = &Bs[1][w * 512];
    __bf16* const bw1_1 = &Bs[1][2048 + w * 512];

    const int wm = (w >> 1) << 6;
    const int wn = (w & 1) << 6;
    const int fr = ln & 15;
    const int fq = (ln >> 4) << 3;

    auto stageA_load = [&](int kt, floatx4& f0, floatx4& f1,
                           floatx4& f2, floatx4& f3) {
        const float* ap = Ag + kt;
        f0 = *(const floatx4*)(ap);
        f1 = *(const floatx4*)(ap + 4);
        f2 = *(const floatx4*)(ap + 8);
        f3 = *(const floatx4*)(ap + 12);
    };
    auto stageA_write = [&](__bf16* dst, floatx4 f0, floatx4 f1,
                            floatx4 f2, floatx4 f3) {
        bf16x8 v0, v1;
        #pragma unroll
        for (int i = 0; i < 4; ++i) {
            v0[i]     = (__bf16)f0[i];
            v0[4 + i] = (__bf16)f1[i];
            v1[i]     = (__bf16)f2[i];
            v1[4 + i] = (__bf16)f3[i];
        }
        *(bf16x8*)dst       = v0;
        *(bf16x8*)(dst + 8) = v1;
    };
    auto stageB = [&](int kt, __bf16* d0, __bf16* d1) {
        gll16(Bm + brow + kt, d0);
        gll16(Bm + brow + (size_t)64 * K_DIM + kt, d1);
    };
    auto compute = [&](const __bf16* AsR, const __bf16* BsR) {
        bf16x8 a[4], b[4];
        #pragma unroll
        for (int mt = 0; mt < 4; ++mt)
            a[mt] = *(const bf16x8*)&AsR[(wm + mt * 16 + fr) * 32 + fq];
        #pragma unroll
        for (int nt = 0; nt < 4; ++nt)
            b[nt] = *(const bf16x8*)&BsR[(wn + nt * 16 + fr) * 32 + fq];
        #pragma unroll
        for (int mt = 0; mt < 4; ++mt)
            #pragma unroll
            for (int nt = 0; nt < 4; ++nt)
                acc[mt][nt] = __builtin_amdgcn_mfma_f32_16x16x32_bf16(
                    a[mt], b[nt], acc[mt][nt], 0, 0, 0);
    };

    // prologue: stage tile kt=0 into buffer 0
    {
        floatx4 f0, f1, f2, f3;
        stageA_load(0, f0, f1, f2, f3);
        stageB(0, bw0_0, bw0_1);
        stageA_write(aw0, f0, f1, f2, f3);
        __syncthreads();
    }

    for (int kt = 0; kt < K_DIM; kt += 64) {
        // phase 0: prefetch kt+32 -> buf1 (always valid), compute buf0
        {
            floatx4 f0, f1, f2, f3;
            stageA_load(kt + 32, f0, f1, f2, f3);
            stageB(kt + 32, bw1_0, bw1_1);
            compute(As[0], Bs[0]);
            stageA_write(aw1, f0, f1, f2, f3);
            __syncthreads();
        }
        // phase 1: prefetch kt+64 -> buf0 (guarded), compute buf1
        {
            const bool pf = (kt + 64) < K_DIM;
            floatx4 f0, f1, f2, f3;
            if (pf) {
                stageA_load(kt + 64, f0, f1, f2, f3);
                stageB(kt + 64, bw0_0, bw0_1);
            }
            compute(As[1], Bs[1]);
            if (pf)
                stageA_write(aw0, f0, f1, f2, f3);
            __syncthreads();
        }
    }

    const int rq = (ln >> 4) * 4;
    #pragma unroll
    for (int mt = 0; mt < 4; ++mt) {
        const int gro = bm * 128 + wm + mt * 16 + rq;
        #pragma unroll
        for (int nt = 0; nt < 4; ++nt) {
            const int gco = bn * 128 + wn + nt * 16 + (ln & 15);
            #pragma unroll
            for (int r = 0; r < 4; ++r)
                Out[(size_t)(gro + r) * 512 + gco] = (__bf16)acc[mt][nt][r];
        }
    }
}

// ---------------------------------------------------------------------------
// GEMM2: out = 2 * X2 * C2^T + D*u.  bf16 A/B via global_load_lds, fp32 out.
// Same double-buffered pipeline.
// ---------------------------------------------------------------------------
__global__ __launch_bounds__(256) void gemm2_kernel(
    const __bf16* __restrict__ A,    // L x 512 bf16 (X2)
    const __bf16* __restrict__ Bm,   // 512 x 512 bf16 (C2)
    float* __restrict__ Out,         // L x 512 fp32
    const float* __restrict__ U,
    const float* __restrict__ Dv)
{
    __shared__ __bf16 As[2][128 * 32];
    __shared__ __bf16 Bs[2][128 * 32];

    const int tid = threadIdx.x;
    const int w  = tid >> 6;
    const int ln = tid & 63;
    const int bm = blockIdx.x;
    const int bn = blockIdx.y;

    floatx4 acc[4][4];
    #pragma unroll
    for (int i = 0; i < 4; ++i)
        #pragma unroll
        for (int j = 0; j < 4; ++j)
            acc[i][j] = (floatx4){0.f, 0.f, 0.f, 0.f};

    const size_t arow = (size_t)(bm * 128 + w * 16 + (ln >> 2)) * K_DIM
                      + ((ln & 3) << 3);
    const size_t brow = (size_t)(bn * 128 + w * 16 + (ln >> 2)) * K_DIM
                      + ((ln & 3) << 3);

    __bf16* const aw0_0 = &As[0][w * 512];
    __bf16* const aw0_1 = &As[0][2048 + w * 512];
    __bf16* const aw1_0 = &As[1][w * 512];
    __bf16* const aw1_1 = &As[1][2048 + w * 512];
    __bf16* const bw0_0 = &Bs[0][w * 512];
    __bf16* const bw0_1 = &Bs[0][2048 + w * 512];
    __bf16* const bw1_0 = &Bs[1][w * 512];
    __bf16* const bw1_1 = &Bs[1][2048 + w * 512];

    const int wm = (w >> 1) << 6;
    const int wn = (w & 1) << 6;
    const int fr = ln & 15;
    const int fq = (ln >> 4) << 3;

    auto stage = [&](int kt, __bf16* a0, __bf16* a1, __bf16* b0, __bf16* b1) {
        gll16(A  + arow + kt, a0);
        gll16(A  + arow + (size_t)64 * K_DIM + kt, a1);
        gll16(Bm + brow + kt, b0);
        gll16(Bm + brow + (size_t)64 * K_DIM + kt, b1);
    };
    auto compute = [&](const __bf16* AsR, const __bf16* BsR) {
        bf16x8 a[4], b[4];
        #pragma unroll
        for (int mt = 0; mt < 4; ++mt)
            a[mt] = *(const bf16x8*)&AsR[(wm + mt * 16 + fr) * 32 + fq];
        #pragma unroll
        for (int nt = 0; nt < 4; ++nt)
            b[nt] = *(const bf16x8*)&BsR[(wn + nt * 16 + fr) * 32 + fq];
        #pragma unroll
        for (int mt = 0; mt < 4; ++mt)
            #pragma unroll
            for (int nt = 0; nt < 4; ++nt)
                acc[mt][nt] = __builtin_amdgcn_mfma_f32_16x16x32_bf16(
                    a[mt], b[nt], acc[mt][nt], 0, 0, 0);
    };

    // prologue
    stage(0, aw0_0, aw0_1, bw0_0, bw0_1);
    __syncthreads();

    for (int kt = 0; kt < K_DIM; kt += 64) {
        // phase 0: prefetch kt+32 -> buf1, compute buf0
        stage(kt + 32, aw1_0, aw1_1, bw1_0, bw1_1);
        compute(As[0], Bs[0]);
        __syncthreads();
        // phase 1: prefetch kt+64 -> buf0 (guarded), compute buf1
        if ((kt + 64) < K_DIM)
            stage(kt + 64, aw0_0, aw0_1, bw0_0, bw0_1);
        compute(As[1], Bs[1]);
        __syncthreads();
    }

    const int rq = (ln >> 4) * 4;
    #pragma unroll
    for (int mt = 0; mt < 4; ++mt) {
        const int gro = bm * 128 + wm + mt * 16 + rq;
        #pragma unroll
        for (int nt = 0; nt < 4; ++nt) {
            const int gco = bn * 128 + wn + nt * 16 + (ln & 15);
            const float dh = Dv[gco];
            #pragma unroll
            for (int r = 0; r < 4; ++r) {
                const size_t o = (size_t)(gro + r) * 512 + gco;
                Out[o] = 2.0f * acc[mt][nt][r] + dh * U[o];
            }
        }
    }
}

// ---------------------------------------------------------------------------
// Chunked scan with register prefetch. G2 interleaved bf16: uint per (l,p).
// WRITE_X==0: aggregates -> Agg[p*NCHUNK+c]. WRITE_X==1: carry -> X in place.
// ---------------------------------------------------------------------------
template <int WRITE_X>
__global__ __launch_bounds__(256) void scan_chunk_kernel(
    const float* __restrict__ dts,
    const float* __restrict__ Lre_g, const float* __restrict__ Lim_g,
    const float* __restrict__ logstep,
    unsigned int* __restrict__ G2u,   // L x 256 uints (bf16 re|im)
    float4* __restrict__ Agg,
    const float2* __restrict__ Carry)
{
    const int p = threadIdx.x;
    const int c = blockIdx.x;
    const int base = c * CHUNK;

    // prefetch: all loads issued before the serial recurrence
    unsigned int g[CHUNK];
    float dt[CHUNK];
    #pragma unroll
    for (int i = 0; i < CHUNK; ++i)
        g[i] = G2u[(size_t)(base + i) * 256 + p];
    #pragma unroll
    for (int i = 0; i < CHUNK; ++i)
        dt[i] = dts[base + i];

    const float lre = Lre_g[p];
    const float lim = Lim_g[p];
    const float stp = __expf(logstep[p]);
    const float inv_den = 1.0f / (lre * lre + lim * lim);

    float Are = 1.0f, Aim = 0.0f;
    float xre, xim;
    if (WRITE_X) {
        float2 cc = Carry[c * P_DIM + p];
        xre = cc.x; xim = cc.y;
    } else {
        xre = 0.0f; xim = 0.0f;
    }

    #pragma unroll
    for (int i = 0; i < CHUNK; ++i) {
        const float d = stp * dt[i];
        const float er = __expf(lre * d);
        float sn, cs;
        __sincosf(lim * d, &sn, &cs);
        const float are = er * cs;
        const float aim = er * sn;
        const float am1 = are - 1.0f;
        const float gr = (am1 * lre + aim * lim) * inv_den;
        const float gi = (aim * lre - am1 * lim) * inv_den;

        const float ure = __uint_as_float(g[i] << 16);
        const float uim = __uint_as_float(g[i] & 0xffff0000u);
        const float bre = gr * ure - gi * uim;
        const float bim = gr * uim + gi * ure;

        const float nxre = are * xre - aim * xim + bre;
        const float nxim = are * xim + aim * xre + bim;
        xre = nxre; xim = nxim;

        if (WRITE_X) {
            __bf16 xr = (__bf16)xre;
            __bf16 xi = (__bf16)xim;
            unsigned int o = (unsigned int)*(unsigned short*)&xr |
                             ((unsigned int)*(unsigned short*)&xi << 16);
            G2u[(size_t)(base + i) * 256 + p] = o;
        } else {
            const float nAre = are * Are - aim * Aim;
            const float nAim = are * Aim + aim * Are;
            Are = nAre; Aim = nAim;
        }
    }

    if (!WRITE_X)
        Agg[p * NCHUNK + c] = make_float4(Are, Aim, xre, xim);
}

// ---------------------------------------------------------------------------
// Kogge-Stone carry scan: one block per channel, one thread per chunk.
// ---------------------------------------------------------------------------
__global__ __launch_bounds__(1024) void carry_kernel(
    const float4* __restrict__ Agg,   // P x NCHUNK
    float2* __restrict__ Carry)       // NCHUNK x P
{
    const int p = blockIdx.x;
    const int c = threadIdx.x;

    __shared__ float sAr[NCHUNK], sAi[NCHUNK], sBr[NCHUNK], sBi[NCHUNK];

    float4 v = Agg[p * NCHUNK + c];
    float ar = v.x, ai = v.y, br = v.z, bi = v.w;
    sAr[c] = ar; sAi[c] = ai; sBr[c] = br; sBi[c] = bi;
    __syncthreads();

    #pragma unroll
    for (int off = 1; off < NCHUNK; off <<= 1) {
        float par, pai, pbr, pbi;
        const bool act = (c >= off);
        if (act) {
            par = sAr[c - off]; pai = sAi[c - off];
            pbr = sBr[c - off]; pbi = sBi[c - off];
        }
        __syncthreads();
        if (act) {
            const float nbr = ar * pbr - ai * pbi + br;
            const float nbi = ar * pbi + ai * pbr + bi;
            const float nar = ar * par - ai * pai;
            const float nai = ar * pai + ai * par;
            ar = nar; ai = nai; br = nbr; bi = nbi;
            sAr[c] = ar; sAi[c] = ai; sBr[c] = br; sBi[c] = bi;
        }
        __syncthreads();
    }

    float cr = 0.0f, ci = 0.0f;
    if (c > 0) { cr = sBr[c - 1]; ci = sBi[c - 1]; }
    Carry[c * P_DIM + p] = make_float2(cr, ci);
}

extern "C" void kernel_launch(void* const* d_in, const int* in_sizes, int n_in,
                              void* d_out, int out_size, void* d_ws, size_t ws_size,
                              hipStream_t stream) {
    const float* U       = (const float*)d_in[0];
    const float* dts     = (const float*)d_in[1];
    const float* Lre     = (const float*)d_in[2];
    const float* Lim     = (const float*)d_in[3];
    const float* Bre     = (const float*)d_in[4];
    const float* Bim     = (const float*)d_in[5];
    const float* Cre     = (const float*)d_in[6];
    const float* Cim     = (const float*)d_in[7];
    const float* Dv      = (const float*)d_in[8];
    const float* logstep = (const float*)d_in[9];
    float* out = (float*)d_out;

    // workspace: G2 (32 MB) + B2 (.5) + C2 (.5) + Agg (4) + Carry (2) = 39 MB
    char* ws = (char*)d_ws;
    __bf16* G2 = (__bf16*)ws;                                 // L x 512 bf16
    __bf16* B2 = (__bf16*)(ws + (size_t)L_SEQ * 512 * 2);
    __bf16* C2 = B2 + 512 * 512;
    float4* Agg = (float4*)(C2 + 512 * 512);
    float2* Carry = (float2*)(Agg + (size_t)P_DIM * NCHUNK);

    build_b2_kernel<<<P_DIM, 512, 0, stream>>>(Bre, Bim, B2);
    build_c2_kernel<<<H_DIM, 256, 0, stream>>>(Cre, Cim, C2);

    dim3 g1(L_SEQ / 128, 4);
    gemm1_kernel<<<g1, 256, 0, stream>>>(U, B2, G2);

    unsigned int* G2u = (unsigned int*)G2;
    scan_chunk_kernel<0><<<NCHUNK, 256, 0, stream>>>(
        dts, Lre, Lim, logstep, G2u, Agg, nullptr);
    carry_kernel<<<P_DIM, NCHUNK, 0, stream>>>(Agg, Carry);
    scan_chunk_kernel<1><<<NCHUNK, 256, 0, stream>>>(
        dts, Lre, Lim, logstep, G2u, nullptr, Carry);

    dim3 g2(L_SEQ / 128, 4);
    gemm2_kernel<<<g2, 256, 0, stream>>>(G2, C2, out, U, Dv);
}

// Round 5
// 245.205 us; speedup vs baseline: 1.0316x; 1.0316x over previous
//
#include <hip/hip_runtime.h>
#include <math.h>

#define L_SEQ 32768
#define H_DIM 512
#define P_DIM 256
#define K_DIM 512
#define CHUNK 32
#define NCHUNK (L_SEQ / CHUNK)   // 1024

typedef __bf16 bf16x8 __attribute__((ext_vector_type(8)));
typedef float floatx4 __attribute__((ext_vector_type(4)));

__device__ __forceinline__ void gll16(const void* g, void* l) {
    __builtin_amdgcn_global_load_lds(
        (__attribute__((address_space(1))) void*)(g),
        (__attribute__((address_space(3))) void*)(l), 16, 0, 0);
}

// B2[2p, h] = Bre[p,h]; B2[2p+1, h] = Bim[p,h]   (512 x 512 bf16)
__global__ __launch_bounds__(512) void build_b2_kernel(
    const float* __restrict__ Bre, const float* __restrict__ Bim,
    __bf16* __restrict__ B2)
{
    const int p = blockIdx.x;     // 0..255
    const int h = threadIdx.x;    // 0..511
    B2[(2 * p) * 512 + h]     = (__bf16)Bre[p * H_DIM + h];
    B2[(2 * p + 1) * 512 + h] = (__bf16)Bim[p * H_DIM + h];
}

// C2[h, 2p] = Cre[h,p]; C2[h, 2p+1] = -Cim[h,p]   (512 x 512 bf16)
__global__ __launch_bounds__(256) void build_c2_kernel(
    const float* __restrict__ Cre, const float* __restrict__ Cim,
    __bf16* __restrict__ C2)
{
    const int h = blockIdx.x;     // 0..511
    const int p = threadIdx.x;    // 0..255
    C2[h * 512 + 2 * p]     = (__bf16)Cre[h * P_DIM + p];
    C2[h * 512 + 2 * p + 1] = (__bf16)(-Cim[h * P_DIM + p]);
}

// ---------------------------------------------------------------------------
// GEMM1: G2[l,j] = sum_h U[l,h]*B2[j,h].  Proven two-barrier skeleton, BK=64
// (8 K-steps, half the barrier-drain events of BK=32).  A: fp32 global ->
// regs -> cvt -> bf16 LDS inside the staging window (the in-window reg wait
// overlaps the B global_load_lds latency barrier #2 drains anyway).
// B via global_load_lds.  LDS 32 KB -> 5 blocks/CU.
// ---------------------------------------------------------------------------
__global__ __launch_bounds__(256) void gemm1_kernel(
    const float* __restrict__ A,     // L x 512 fp32 (U)
    const __bf16* __restrict__ Bm,   // 512 x 512 bf16 (B2)
    __bf16* __restrict__ Out)        // L x 512 bf16 (G2)
{
    __shared__ __bf16 As[128 * 64];   // 16 KB
    __shared__ __bf16 Bs[128 * 64];   // 16 KB

    const int tid = threadIdx.x;
    const int w  = tid >> 6;
    const int ln = tid & 63;
    const int bm = blockIdx.x;
    const int bn = blockIdx.y;

    floatx4 acc[4][4];
    #pragma unroll
    for (int i = 0; i < 4; ++i)
        #pragma unroll
        for (int j = 0; j < 4; ++j)
            acc[i][j] = (floatx4){0.f, 0.f, 0.f, 0.f};

    // A reg-staging: thread t -> row t>>1, col-half (t&1)*32 (32 fp32 = 128 B)
    const int ar = tid >> 1;
    const int ach = (tid & 1) << 5;
    const float* Ag = A + (size_t)(bm * 128 + ar) * K_DIM + ach;
    __bf16* const aw = &As[ar * 64 + ach];

    // B via gll16: wave w, issue q -> rows q*32 + w*8 + (ln>>3), col (ln&7)*8
    const size_t brow = (size_t)(bn * 128 + w * 8 + (ln >> 3)) * K_DIM
                      + ((ln & 7) << 3);

    const int wm = (w >> 1) << 6;
    const int wn = (w & 1) << 6;
    const int fr = ln & 15;
    const int fq = (ln >> 4) << 3;

    for (int kt = 0; kt < K_DIM; kt += 64) {
        __syncthreads();   // barrier 1: previous compute's LDS reads done

        // A: 8x dwordx4 -> regs (issued first; B gll16 latency overlaps wait)
        floatx4 fa[8];
        const float* ap = Ag + kt;
        #pragma unroll
        for (int i = 0; i < 8; ++i)
            fa[i] = *(const floatx4*)(ap + i * 4);

        // B: 4 gll16 per wave
        #pragma unroll
        for (int q = 0; q < 4; ++q)
            gll16(Bm + brow + (size_t)q * 32 * K_DIM + kt,
                  Bs + (q * 32 + w * 8) * 64);

        // cvt + ds_write A (compiler inserts the vmcnt wait for fa here)
        #pragma unroll
        for (int i = 0; i < 4; ++i) {
            bf16x8 v;
            #pragma unroll
            for (int j = 0; j < 4; ++j) {
                v[j]     = (__bf16)fa[2 * i][j];
                v[4 + j] = (__bf16)fa[2 * i + 1][j];
            }
            *(bf16x8*)(aw + i * 8) = v;
        }

        __syncthreads();   // barrier 2: staging (vmcnt + lgkmcnt) drained

        #pragma unroll
        for (int kk = 0; kk < 64; kk += 32) {
            bf16x8 a[4], b[4];
            #pragma unroll
            for (int mt = 0; mt < 4; ++mt)
                a[mt] = *(const bf16x8*)&As[(wm + mt * 16 + fr) * 64 + kk + fq];
            #pragma unroll
            for (int nt = 0; nt < 4; ++nt)
                b[nt] = *(const bf16x8*)&Bs[(wn + nt * 16 + fr) * 64 + kk + fq];
            #pragma unroll
            for (int mt = 0; mt < 4; ++mt)
                #pragma unroll
                for (int nt = 0; nt < 4; ++nt)
                    acc[mt][nt] = __builtin_amdgcn_mfma_f32_16x16x32_bf16(
                        a[mt], b[nt], acc[mt][nt], 0, 0, 0);
        }
    }

    const int rq = (ln >> 4) * 4;
    #pragma unroll
    for (int mt = 0; mt < 4; ++mt) {
        const int gro = bm * 128 + wm + mt * 16 + rq;
        #pragma unroll
        for (int nt = 0; nt < 4; ++nt) {
            const int gco = bn * 128 + wn + nt * 16 + (ln & 15);
            #pragma unroll
            for (int r = 0; r < 4; ++r)
                Out[(size_t)(gro + r) * 512 + gco] = (__bf16)acc[mt][nt][r];
        }
    }
}

// ---------------------------------------------------------------------------
// GEMM2: out = 2 * X2 * C2^T + D*u.  Proven two-barrier skeleton, BK=64.
// bf16 A/B both via global_load_lds (8 per wave per K-step), fp32 out.
// ---------------------------------------------------------------------------
__global__ __launch_bounds__(256) void gemm2_kernel(
    const __bf16* __restrict__ A,    // L x 512 bf16 (X2)
    const __bf16* __restrict__ Bm,   // 512 x 512 bf16 (C2)
    float* __restrict__ Out,         // L x 512 fp32
    const float* __restrict__ U,
    const float* __restrict__ Dv)
{
    __shared__ __bf16 As[128 * 64];   // 16 KB
    __shared__ __bf16 Bs[128 * 64];   // 16 KB

    const int tid = threadIdx.x;
    const int w  = tid >> 6;
    const int ln = tid & 63;
    const int bm = blockIdx.x;
    const int bn = blockIdx.y;

    floatx4 acc[4][4];
    #pragma unroll
    for (int i = 0; i < 4; ++i)
        #pragma unroll
        for (int j = 0; j < 4; ++j)
            acc[i][j] = (floatx4){0.f, 0.f, 0.f, 0.f};

    const size_t arow = (size_t)(bm * 128 + w * 8 + (ln >> 3)) * K_DIM
                      + ((ln & 7) << 3);
    const size_t brow = (size_t)(bn * 128 + w * 8 + (ln >> 3)) * K_DIM
                      + ((ln & 7) << 3);

    const int wm = (w >> 1) << 6;
    const int wn = (w & 1) << 6;
    const int fr = ln & 15;
    const int fq = (ln >> 4) << 3;

    for (int kt = 0; kt < K_DIM; kt += 64) {
        __syncthreads();
        #pragma unroll
        for (int q = 0; q < 4; ++q)
            gll16(A + arow + (size_t)q * 32 * K_DIM + kt,
                  As + (q * 32 + w * 8) * 64);
        #pragma unroll
        for (int q = 0; q < 4; ++q)
            gll16(Bm + brow + (size_t)q * 32 * K_DIM + kt,
                  Bs + (q * 32 + w * 8) * 64);
        __syncthreads();

        #pragma unroll
        for (int kk = 0; kk < 64; kk += 32) {
            bf16x8 a[4], b[4];
            #pragma unroll
            for (int mt = 0; mt < 4; ++mt)
                a[mt] = *(const bf16x8*)&As[(wm + mt * 16 + fr) * 64 + kk + fq];
            #pragma unroll
            for (int nt = 0; nt < 4; ++nt)
                b[nt] = *(const bf16x8*)&Bs[(wn + nt * 16 + fr) * 64 + kk + fq];
            #pragma unroll
            for (int mt = 0; mt < 4; ++mt)
                #pragma unroll
                for (int nt = 0; nt < 4; ++nt)
                    acc[mt][nt] = __builtin_amdgcn_mfma_f32_16x16x32_bf16(
                        a[mt], b[nt], acc[mt][nt], 0, 0, 0);
        }
    }

    const int rq = (ln >> 4) * 4;
    #pragma unroll
    for (int mt = 0; mt < 4; ++mt) {
        const int gro = bm * 128 + wm + mt * 16 + rq;
        #pragma unroll
        for (int nt = 0; nt < 4; ++nt) {
            const int gco = bn * 128 + wn + nt * 16 + (ln & 15);
            const float dh = Dv[gco];
            #pragma unroll
            for (int r = 0; r < 4; ++r) {
                const size_t o = (size_t)(gro + r) * 512 + gco;
                Out[o] = 2.0f * acc[mt][nt][r] + dh * U[o];
            }
        }
    }
}

// ---------------------------------------------------------------------------
// Chunked scan with register prefetch. G2 interleaved bf16: uint per (l,p).
// WRITE_X==0: aggregates -> Agg[p*NCHUNK+c]. WRITE_X==1: carry -> X in place.
// ---------------------------------------------------------------------------
template <int WRITE_X>
__global__ __launch_bounds__(256) void scan_chunk_kernel(
    const float* __restrict__ dts,
    const float* __restrict__ Lre_g, const float* __restrict__ Lim_g,
    const float* __restrict__ logstep,
    unsigned int* __restrict__ G2u,   // L x 256 uints (bf16 re|im)
    float4* __restrict__ Agg,
    const float2* __restrict__ Carry)
{
    const int p = threadIdx.x;
    const int c = blockIdx.x;
    const int base = c * CHUNK;

    // prefetch: all loads issued before the serial recurrence
    unsigned int g[CHUNK];
    float dt[CHUNK];
    #pragma unroll
    for (int i = 0; i < CHUNK; ++i)
        g[i] = G2u[(size_t)(base + i) * 256 + p];
    #pragma unroll
    for (int i = 0; i < CHUNK; ++i)
        dt[i] = dts[base + i];

    const float lre = Lre_g[p];
    const float lim = Lim_g[p];
    const float stp = __expf(logstep[p]);
    const float inv_den = 1.0f / (lre * lre + lim * lim);

    float Are = 1.0f, Aim = 0.0f;
    float xre, xim;
    if (WRITE_X) {
        float2 cc = Carry[c * P_DIM + p];
        xre = cc.x; xim = cc.y;
    } else {
        xre = 0.0f; xim = 0.0f;
    }

    #pragma unroll
    for (int i = 0; i < CHUNK; ++i) {
        const float d = stp * dt[i];
        const float er = __expf(lre * d);
        float sn, cs;
        __sincosf(lim * d, &sn, &cs);
        const float are = er * cs;
        const float aim = er * sn;
        const float am1 = are - 1.0f;
        const float gr = (am1 * lre + aim * lim) * inv_den;
        const float gi = (aim * lre - am1 * lim) * inv_den;

        const float ure = __uint_as_float(g[i] << 16);
        const float uim = __uint_as_float(g[i] & 0xffff0000u);
        const float bre = gr * ure - gi * uim;
        const float bim = gr * uim + gi * ure;

        const float nxre = are * xre - aim * xim + bre;
        const float nxim = are * xim + aim * xre + bim;
        xre = nxre; xim = nxim;

        if (WRITE_X) {
            __bf16 xr = (__bf16)xre;
            __bf16 xi = (__bf16)xim;
            unsigned int o = (unsigned int)*(unsigned short*)&xr |
                             ((unsigned int)*(unsigned short*)&xi << 16);
            G2u[(size_t)(base + i) * 256 + p] = o;
        } else {
            const float nAre = are * Are - aim * Aim;
            const float nAim = are * Aim + aim * Are;
            Are = nAre; Aim = nAim;
        }
    }

    if (!WRITE_X)
        Agg[p * NCHUNK + c] = make_float4(Are, Aim, xre, xim);
}

// ---------------------------------------------------------------------------
// Kogge-Stone carry scan: one block per channel, one thread per chunk.
// ---------------------------------------------------------------------------
__global__ __launch_bounds__(1024) void carry_kernel(
    const float4* __restrict__ Agg,   // P x NCHUNK
    float2* __restrict__ Carry)       // NCHUNK x P
{
    const int p = blockIdx.x;
    const int c = threadIdx.x;

    __shared__ float sAr[NCHUNK], sAi[NCHUNK], sBr[NCHUNK], sBi[NCHUNK];

    float4 v = Agg[p * NCHUNK + c];
    float ar = v.x, ai = v.y, br = v.z, bi = v.w;
    sAr[c] = ar; sAi[c] = ai; sBr[c] = br; sBi[c] = bi;
    __syncthreads();

    #pragma unroll
    for (int off = 1; off < NCHUNK; off <<= 1) {
        float par, pai, pbr, pbi;
        const bool act = (c >= off);
        if (act) {
            par = sAr[c - off]; pai = sAi[c - off];
            pbr = sBr[c - off]; pbi = sBi[c - off];
        }
        __syncthreads();
        if (act) {
            const float nbr = ar * pbr - ai * pbi + br;
            const float nbi = ar * pbi + ai * pbr + bi;
            const float nar = ar * par - ai * pai;
            const float nai = ar * pai + ai * par;
            ar = nar; ai = nai; br = nbr; bi = nbi;
            sAr[c] = ar; sAi[c] = ai; sBr[c] = br; sBi[c] = bi;
        }
        __syncthreads();
    }

    float cr = 0.0f, ci = 0.0f;
    if (c > 0) { cr = sBr[c - 1]; ci = sBi[c - 1]; }
    Carry[c * P_DIM + p] = make_float2(cr, ci);
}

extern "C" void kernel_launch(void* const* d_in, const int* in_sizes, int n_in,
                              void* d_out, int out_size, void* d_ws, size_t ws_size,
                              hipStream_t stream) {
    const float* U       = (const float*)d_in[0];
    const float* dts     = (const float*)d_in[1];
    const float* Lre     = (const float*)d_in[2];
    const float* Lim     = (const float*)d_in[3];
    const float* Bre     = (const float*)d_in[4];
    const float* Bim     = (const float*)d_in[5];
    const float* Cre     = (const float*)d_in[6];
    const float* Cim     = (const float*)d_in[7];
    const float* Dv      = (const float*)d_in[8];
    const float* logstep = (const float*)d_in[9];
    float* out = (float*)d_out;

    // workspace: G2 (32 MB) + B2 (.5) + C2 (.5) + Agg (4) + Carry (2) = 39 MB
    char* ws = (char*)d_ws;
    __bf16* G2 = (__bf16*)ws;                                 // L x 512 bf16
    __bf16* B2 = (__bf16*)(ws + (size_t)L_SEQ * 512 * 2);
    __bf16* C2 = B2 + 512 * 512;
    float4* Agg = (float4*)(C2 + 512 * 512);
    float2* Carry = (float2*)(Agg + (size_t)P_DIM * NCHUNK);

    build_b2_kernel<<<P_DIM, 512, 0, stream>>>(Bre, Bim, B2);
    build_c2_kernel<<<H_DIM, 256, 0, stream>>>(Cre, Cim, C2);

    dim3 g1(L_SEQ / 128, 4);
    gemm1_kernel<<<g1, 256, 0, stream>>>(U, B2, G2);

    unsigned int* G2u = (unsigned int*)G2;
    scan_chunk_kernel<0><<<NCHUNK, 256, 0, stream>>>(
        dts, Lre, Lim, logstep, G2u, Agg, nullptr);
    carry_kernel<<<P_DIM, NCHUNK, 0, stream>>>(Agg, Carry);
    scan_chunk_kernel<1><<<NCHUNK, 256, 0, stream>>>(
        dts, Lre, Lim, logstep, G2u, nullptr, Carry);

    dim3 g2(L_SEQ / 128, 4);
    gemm2_kernel<<<g2, 256, 0, stream>>>(G2, C2, out, U, Dv);
}

// Round 7
// 228.263 us; speedup vs baseline: 1.1082x; 1.0742x over previous
//
#include <hip/hip_runtime.h>
#include <math.h>

#define L_SEQ 32768
#define H_DIM 512
#define P_DIM 256
#define K_DIM 512
#define CHUNK 32
#define NCHUNK (L_SEQ / CHUNK)   // 1024

typedef __bf16 bf16x8 __attribute__((ext_vector_type(8)));
typedef float floatx4 __attribute__((ext_vector_type(4)));

__device__ __forceinline__ void gll16(const void* g, void* l) {
    __builtin_amdgcn_global_load_lds(
        (__attribute__((address_space(1))) void*)(g),
        (__attribute__((address_space(3))) void*)(l), 16, 0, 0);
}

// Fused builders (proven r5).
// blocks 0..255:   B2[2p, h] = Bre[p,h]; B2[2p+1, h] = Bim[p,h]
// blocks 256..767: C2[h, 2p] = Cre[h,p]; C2[h, 2p+1] = -Cim[h,p]
__global__ __launch_bounds__(512) void build_kernel(
    const float* __restrict__ Bre, const float* __restrict__ Bim,
    const float* __restrict__ Cre, const float* __restrict__ Cim,
    __bf16* __restrict__ B2, __bf16* __restrict__ C2)
{
    const int b = blockIdx.x;
    const int t = threadIdx.x;
    if (b < 256) {
        B2[(2 * b) * 512 + t]     = (__bf16)Bre[b * H_DIM + t];
        B2[(2 * b + 1) * 512 + t] = (__bf16)Bim[b * H_DIM + t];
    } else {
        const int h = b - 256;
        const int p = t & 255;
        if (t < 256)
            C2[h * 512 + 2 * p]     = (__bf16)Cre[h * P_DIM + p];
        else
            C2[h * 512 + 2 * p + 1] = (__bf16)(-Cim[h * P_DIM + p]);
    }
}

// ---------------------------------------------------------------------------
// GEMM1 (r0-exact, proven 53 us): G2[l,j] = sum_h U[l,h]*B2[j,h].
// ---------------------------------------------------------------------------
__global__ __launch_bounds__(256) void gemm1_kernel(
    const float* __restrict__ A,     // L x 512 fp32 (U)
    const __bf16* __restrict__ Bm,   // 512 x 512 bf16 (B2)
    __bf16* __restrict__ Out)        // L x 512 bf16 (G2)
{
    __shared__ float  Asf[128 * 32];   // 16 KB
    __shared__ __bf16 Bs [128 * 32];   // 8 KB

    const int tid = threadIdx.x;
    const int w  = tid >> 6;
    const int ln = tid & 63;
    const int bm = blockIdx.x;
    const int bn = blockIdx.y;

    floatx4 acc[4][4];
    #pragma unroll
    for (int i = 0; i < 4; ++i)
        #pragma unroll
        for (int j = 0; j < 4; ++j)
            acc[i][j] = (floatx4){0.f, 0.f, 0.f, 0.f};

    const int a_r = ln >> 3;
    const int a_c = (ln & 7) << 2;
    const int b_r = ln >> 2;
    const int b_c = (ln & 3) << 3;
    const size_t brow = (size_t)(bn * 128 + w * 16 + b_r) * K_DIM;

    float*  lA[4];
    size_t  gAr[4];
    #pragma unroll
    for (int q = 0; q < 4; ++q) {
        lA[q] = Asf + (q * 32 + w * 8) * 32;
        gAr[q] = (size_t)(bm * 128 + q * 32 + w * 8 + a_r) * K_DIM;
    }
    __bf16* lB0 = Bs + w * 512;
    __bf16* lB1 = Bs + 2048 + w * 512;

    const int wm = (w >> 1) * 64;
    const int wn = (w & 1) * 64;
    const int fr = ln & 15;
    const int fq = (ln >> 4) * 8;

    for (int kt = 0; kt < K_DIM; kt += 32) {
        __syncthreads();
        #pragma unroll
        for (int q = 0; q < 4; ++q)
            gll16(A + gAr[q] + kt + a_c, lA[q]);
        gll16(Bm + brow + kt + b_c,                      lB0);
        gll16(Bm + brow + (size_t)64 * K_DIM + kt + b_c, lB1);
        __syncthreads();

        bf16x8 a[4], b[4];
        #pragma unroll
        for (int mt = 0; mt < 4; ++mt) {
            floatx4 a0 = *(floatx4*)&Asf[(wm + mt * 16 + fr) * 32 + fq];
            floatx4 a1 = *(floatx4*)&Asf[(wm + mt * 16 + fr) * 32 + fq + 4];
            #pragma unroll
            for (int r = 0; r < 4; ++r) {
                a[mt][r]     = (__bf16)a0[r];
                a[mt][4 + r] = (__bf16)a1[r];
            }
        }
        #pragma unroll
        for (int nt = 0; nt < 4; ++nt)
            b[nt] = *(bf16x8*)&Bs[(wn + nt * 16 + fr) * 32 + fq];

        #pragma unroll
        for (int mt = 0; mt < 4; ++mt)
            #pragma unroll
            for (int nt = 0; nt < 4; ++nt)
                acc[mt][nt] = __builtin_amdgcn_mfma_f32_16x16x32_bf16(
                    a[mt], b[nt], acc[mt][nt], 0, 0, 0);
    }

    const int rq = (ln >> 4) * 4;
    #pragma unroll
    for (int mt = 0; mt < 4; ++mt) {
        const int gro = bm * 128 + wm + mt * 16 + rq;
        #pragma unroll
        for (int nt = 0; nt < 4; ++nt) {
            const int gco = bn * 128 + wn + nt * 16 + (ln & 15);
            #pragma unroll
            for (int r = 0; r < 4; ++r)
                Out[(size_t)(gro + r) * 512 + gco] = (__bf16)acc[mt][nt][r];
        }
    }
}

// ---------------------------------------------------------------------------
// GEMM2 (r0-exact, proven ~50 us): out = 2 * X2 * C2^T + D*u.
// ---------------------------------------------------------------------------
__global__ __launch_bounds__(256) void gemm2_kernel(
    const __bf16* __restrict__ A,    // L x 512 bf16 (X2)
    const __bf16* __restrict__ Bm,   // 512 x 512 bf16 (C2)
    float* __restrict__ Out,         // L x 512 fp32
    const float* __restrict__ U,
    const float* __restrict__ Dv)
{
    __shared__ __bf16 As[128 * 32];
    __shared__ __bf16 Bs[128 * 32];

    const int tid = threadIdx.x;
    const int w  = tid >> 6;
    const int ln = tid & 63;
    const int bm = blockIdx.x;
    const int bn = blockIdx.y;

    floatx4 acc[4][4];
    #pragma unroll
    for (int i = 0; i < 4; ++i)
        #pragma unroll
        for (int j = 0; j < 4; ++j)
            acc[i][j] = (floatx4){0.f, 0.f, 0.f, 0.f};

    const int lr = ln >> 2;
    const int lce = (ln & 3) << 3;
    const size_t arow = (size_t)(bm * 128 + w * 16 + lr) * K_DIM;
    const size_t brow = (size_t)(bn * 128 + w * 16 + lr) * K_DIM;

    __bf16* lA0 = As + w * 512;
    __bf16* lA1 = As + 2048 + w * 512;
    __bf16* lB0 = Bs + w * 512;
    __bf16* lB1 = Bs + 2048 + w * 512;

    const int wm = (w >> 1) * 64;
    const int wn = (w & 1) * 64;
    const int fr = ln & 15;
    const int fq = (ln >> 4) * 8;

    for (int kt = 0; kt < K_DIM; kt += 32) {
        __syncthreads();
        gll16(A  + arow + kt + lce,                      lA0);
        gll16(A  + arow + (size_t)64 * K_DIM + kt + lce, lA1);
        gll16(Bm + brow + kt + lce,                      lB0);
        gll16(Bm + brow + (size_t)64 * K_DIM + kt + lce, lB1);
        __syncthreads();

        bf16x8 a[4], b[4];
        #pragma unroll
        for (int mt = 0; mt < 4; ++mt)
            a[mt] = *(bf16x8*)&As[(wm + mt * 16 + fr) * 32 + fq];
        #pragma unroll
        for (int nt = 0; nt < 4; ++nt)
            b[nt] = *(bf16x8*)&Bs[(wn + nt * 16 + fr) * 32 + fq];

        #pragma unroll
        for (int mt = 0; mt < 4; ++mt)
            #pragma unroll
            for (int nt = 0; nt < 4; ++nt)
                acc[mt][nt] = __builtin_amdgcn_mfma_f32_16x16x32_bf16(
                    a[mt], b[nt], acc[mt][nt], 0, 0, 0);
    }

    const int rq = (ln >> 4) * 4;
    #pragma unroll
    for (int mt = 0; mt < 4; ++mt) {
        const int gro = bm * 128 + wm + mt * 16 + rq;
        #pragma unroll
        for (int nt = 0; nt < 4; ++nt) {
            const int gco = bn * 128 + wn + nt * 16 + (ln & 15);
            const float dh = Dv[gco];
            #pragma unroll
            for (int r = 0; r < 4; ++r) {
                const size_t o = (size_t)(gro + r) * 512 + gco;
                Out[o] = 2.0f * acc[mt][nt][r] + dh * U[o];
            }
        }
    }
}

// ---------------------------------------------------------------------------
// Chunked scan (r0-exact proven). G2 interleaved bf16: uint per (l,p).
// WRITE_X==0: aggregates -> Agg[p*NCHUNK+c]. WRITE_X==1: carry -> X in place.
// ---------------------------------------------------------------------------
template <int WRITE_X>
__global__ __launch_bounds__(256) void scan_chunk_kernel(
    const float* __restrict__ dts,
    const float* __restrict__ Lre_g, const float* __restrict__ Lim_g,
    const float* __restrict__ logstep,
    unsigned int* __restrict__ G2u,   // L x 256 uints (bf16 re|im)
    float4* __restrict__ Agg,
    const float2* __restrict__ Carry)
{
    const int p = threadIdx.x;
    const int c = blockIdx.x;
    const int base = c * CHUNK;

    unsigned int g[CHUNK];
    float dt[CHUNK];
    #pragma unroll
    for (int i = 0; i < CHUNK; ++i)
        g[i] = G2u[(size_t)(base + i) * 256 + p];
    #pragma unroll
    for (int i = 0; i < CHUNK; ++i)
        dt[i] = dts[base + i];

    const float lre = Lre_g[p];
    const float lim = Lim_g[p];
    const float stp = __expf(logstep[p]);
    const float inv_den = 1.0f / (lre * lre + lim * lim);

    float Are = 1.0f, Aim = 0.0f;
    float xre, xim;
    if (WRITE_X) {
        float2 cc = Carry[c * P_DIM + p];
        xre = cc.x; xim = cc.y;
    } else {
        xre = 0.0f; xim = 0.0f;
    }

    #pragma unroll
    for (int i = 0; i < CHUNK; ++i) {
        const float d = stp * dt[i];
        const float er = __expf(lre * d);
        float sn, cs;
        __sincosf(lim * d, &sn, &cs);
        const float are = er * cs;
        const float aim = er * sn;
        const float am1 = are - 1.0f;
        const float gr = (am1 * lre + aim * lim) * inv_den;
        const float gi = (aim * lre - am1 * lim) * inv_den;

        const float ure = __uint_as_float(g[i] << 16);
        const float uim = __uint_as_float(g[i] & 0xffff0000u);
        const float bre = gr * ure - gi * uim;
        const float bim = gr * uim + gi * ure;

        const float nxre = are * xre - aim * xim + bre;
        const float nxim = are * xim + aim * xre + bim;
        xre = nxre; xim = nxim;

        if (WRITE_X) {
            __bf16 xr = (__bf16)xre;
            __bf16 xi = (__bf16)xim;
            unsigned int o = (unsigned int)*(unsigned short*)&xr |
                             ((unsigned int)*(unsigned short*)&xi << 16);
            G2u[(size_t)(base + i) * 256 + p] = o;
        } else {
            const float nAre = are * Are - aim * Aim;
            const float nAim = are * Aim + aim * Are;
            Are = nAre; Aim = nAim;
        }
    }

    if (!WRITE_X)
        Agg[p * NCHUNK + c] = make_float4(Are, Aim, xre, xim);
}

// ---------------------------------------------------------------------------
// Carry scan via shfl (replaces 1024-thread Kogge-Stone: 6 shfl rounds +
// 1 barrier instead of 20 barriers x 16 waves).  Block = channel; 256
// threads, 4 chunk-aggregates each; non-commutative affine compose.
// ---------------------------------------------------------------------------
struct CT { float Ar, Ai, br, bi; };   // x -> A*x + b  (complex)

__device__ __forceinline__ CT ct_compose(const CT& f, const CT& s) {
    // apply f first, then s
    CT r;
    r.Ar = s.Ar * f.Ar - s.Ai * f.Ai;
    r.Ai = s.Ar * f.Ai + s.Ai * f.Ar;
    r.br = s.Ar * f.br - s.Ai * f.bi + s.br;
    r.bi = s.Ar * f.bi + s.Ai * f.br + s.bi;
    return r;
}

__global__ __launch_bounds__(256) void carry_shfl_kernel(
    const float4* __restrict__ Agg,   // P x NCHUNK
    float2* __restrict__ Carry)       // NCHUNK x P
{
    const int pch = blockIdx.x;       // channel
    const int t  = threadIdx.x;       // 0..255, 4 chunks each
    const int ln = t & 63;
    const int wv = t >> 6;

    __shared__ float4 wtot[4];

    CT v[4];
    #pragma unroll
    for (int i = 0; i < 4; ++i) {
        float4 f = Agg[(size_t)pch * NCHUNK + 4 * t + i];
        v[i].Ar = f.x; v[i].Ai = f.y; v[i].br = f.z; v[i].bi = f.w;
    }
    // thread aggregate (earlier chunk first)
    CT val = v[0];
    #pragma unroll
    for (int i = 1; i < 4; ++i) val = ct_compose(val, v[i]);

    // inclusive wave scan (non-commutative; earlier lane applied first)
    #pragma unroll
    for (int off = 1; off < 64; off <<= 1) {
        CT o;
        o.Ar = __shfl_up(val.Ar, off);
        o.Ai = __shfl_up(val.Ai, off);
        o.br = __shfl_up(val.br, off);
        o.bi = __shfl_up(val.bi, off);
        if (ln >= off) val = ct_compose(o, val);
    }

    // lane-exclusive
    CT lexcl;
    lexcl.Ar = __shfl_up(val.Ar, 1);
    lexcl.Ai = __shfl_up(val.Ai, 1);
    lexcl.br = __shfl_up(val.br, 1);
    lexcl.bi = __shfl_up(val.bi, 1);
    if (ln == 0) { lexcl.Ar = 1.f; lexcl.Ai = 0.f; lexcl.br = 0.f; lexcl.bi = 0.f; }

    if (ln == 63) wtot[wv] = make_float4(val.Ar, val.Ai, val.br, val.bi);
    __syncthreads();

    CT wpre; wpre.Ar = 1.f; wpre.Ai = 0.f; wpre.br = 0.f; wpre.bi = 0.f;
    for (int i = 0; i < wv; ++i) {
        float4 f = wtot[i];
        CT tt; tt.Ar = f.x; tt.Ai = f.y; tt.br = f.z; tt.bi = f.w;
        wpre = ct_compose(wpre, tt);
    }

    CT E = ct_compose(wpre, lexcl);   // composite of chunks < 4t
    #pragma unroll
    for (int i = 0; i < 4; ++i) {
        Carry[(size_t)(4 * t + i) * P_DIM + pch] = make_float2(E.br, E.bi);
        E = ct_compose(E, v[i]);
    }
}

extern "C" void kernel_launch(void* const* d_in, const int* in_sizes, int n_in,
                              void* d_out, int out_size, void* d_ws, size_t ws_size,
                              hipStream_t stream) {
    const float* U       = (const float*)d_in[0];
    const float* dts     = (const float*)d_in[1];
    const float* Lre     = (const float*)d_in[2];
    const float* Lim     = (const float*)d_in[3];
    const float* Bre     = (const float*)d_in[4];
    const float* Bim     = (const float*)d_in[5];
    const float* Cre     = (const float*)d_in[6];
    const float* Cim     = (const float*)d_in[7];
    const float* Dv      = (const float*)d_in[8];
    const float* logstep = (const float*)d_in[9];
    float* out = (float*)d_out;

    // workspace: G2 (32 MB) + B2 (.5) + C2 (.5) + Agg (4) + Carry (2) = 39 MB
    char* ws = (char*)d_ws;
    __bf16* G2 = (__bf16*)ws;                                 // L x 512 bf16
    __bf16* B2 = (__bf16*)(ws + (size_t)L_SEQ * 512 * 2);
    __bf16* C2 = B2 + 512 * 512;
    float4* Agg = (float4*)(C2 + 512 * 512);
    float2* Carry = (float2*)(Agg + (size_t)P_DIM * NCHUNK);

    build_kernel<<<768, 512, 0, stream>>>(Bre, Bim, Cre, Cim, B2, C2);

    dim3 g1(L_SEQ / 128, 4);
    gemm1_kernel<<<g1, 256, 0, stream>>>(U, B2, G2);

    unsigned int* G2u = (unsigned int*)G2;
    scan_chunk_kernel<0><<<NCHUNK, 256, 0, stream>>>(
        dts, Lre, Lim, logstep, G2u, Agg, nullptr);
    carry_shfl_kernel<<<P_DIM, 256, 0, stream>>>(Agg, Carry);
    scan_chunk_kernel<1><<<NCHUNK, 256, 0, stream>>>(
        dts, Lre, Lim, logstep, G2u, nullptr, Carry);

    dim3 g2(L_SEQ / 128, 4);
    gemm2_kernel<<<g2, 256, 0, stream>>>(G2, C2, out, U, Dv);
}